// Round 1
// baseline (504.081 us; speedup 1.0000x reference)
//
#include <hip/hip_runtime.h>

#define N_NODES  131072
#define N_GRAPHS 4096
#define HID      512
#define NPG      32      // nodes per graph (consecutive)
#define LDH      520     // padded LDS row stride in bf16 elems (1040 B -> bank step 4)

typedef float  f32x4  __attribute__((ext_vector_type(4)));
typedef __bf16 bf16x8 __attribute__((ext_vector_type(8)));

__device__ __forceinline__ unsigned short f2bf(float f) {
  unsigned int u = __builtin_bit_cast(unsigned int, f);
  u += 0x7FFFu + ((u >> 16) & 1u);   // round-to-nearest-even
  return (unsigned short)(u >> 16);
}

__device__ __forceinline__ f32x4 mfma_bf16(bf16x8 a, bf16x8 b, f32x4 c) {
  return __builtin_amdgcn_mfma_f32_16x16x32_bf16(a, b, c, 0, 0, 0);
}

// ---------------- prep: W[b][k][n] fp32 -> WT[b][n][k] bf16 (512x512, Wn1 & Ws) ----
__global__ __launch_bounds__(256) void prep_t512_kernel(
    const float* __restrict__ Wn1, const float* __restrict__ Ws,
    unsigned short* __restrict__ W1T, unsigned short* __restrict__ WsT) {
  __shared__ unsigned short lt[32][33];
  const int bid = blockIdx.x;          // 2048 blocks
  const int which = bid >> 10;         // 0: Wn1->W1T, 1: Ws->WsT
  const int b  = (bid >> 8) & 3;
  const int ti = (bid >> 4) & 15;      // k tile
  const int tj = bid & 15;             // n tile
  const float* src = which ? Ws : Wn1;
  unsigned short* dst = which ? WsT : W1T;
  const int t = threadIdx.x;
  const int c = t & 31;
  const int r0 = (t >> 5) * 4;
  #pragma unroll
  for (int rr = 0; rr < 4; ++rr) {
    int row = r0 + rr;
    lt[row][c] = f2bf(src[(b * 512 + ti * 32 + row) * 512 + tj * 32 + c]);
  }
  __syncthreads();
  #pragma unroll
  for (int rr = 0; rr < 4; ++rr) {
    int row = r0 + rr;
    dst[(b * 512 + tj * 32 + row) * 512 + ti * 32 + c] = lt[c][row];
  }
}

// ---------------- prep: Wn2 (4,512,6)->[b][16][512] bf16 zero-pad; Wg (4,512,100)->[b][128][512]
__global__ __launch_bounds__(256) void prep_small_kernel(
    const float* __restrict__ Wn2, const float* __restrict__ Wg,
    unsigned short* __restrict__ W2T, unsigned short* __restrict__ WgT) {
  int idx = blockIdx.x * 256 + threadIdx.x;
  if (idx < 4 * 16 * 512) {
    int b = idx >> 13;
    int r = (idx >> 9) & 15;
    int k = idx & 511;
    float v = (r < 6) ? Wn2[(b * 512 + k) * 6 + r] : 0.f;
    W2T[idx] = f2bf(v);
  }
  int idx2 = idx - 4 * 16 * 512;
  if (idx2 >= 0 && idx2 < 4 * 128 * 512) {
    int b = idx2 >> 16;
    int r = (idx2 >> 9) & 127;
    int k = idx2 & 511;
    float v = (r < 100) ? Wg[(b * 512 + k) * 100 + r] : 0.f;
    WgT[idx2] = f2bf(v);
  }
}

// ---------------- node MLP: 1 block = 1 graph (32 rows, uniform branch) -------------
__global__ __launch_bounds__(256, 2) void node_kernel(
    const float* __restrict__ x,
    const float* __restrict__ bn1,
    const float* __restrict__ bn2,
    const int* __restrict__ dsid,
    const unsigned short* __restrict__ W1T,   // [b][n=512][k=512] bf16
    const unsigned short* __restrict__ W2T,   // [b][16][512] bf16 (rows 6..15 zero)
    unsigned short* __restrict__ xg,          // out: [4096][512] bf16 graph means
    float* __restrict__ n_head,
    float* __restrict__ n_var) {
  __shared__ __align__(16) unsigned short tile[32 * LDH];  // x, later h
  __shared__ __align__(16) float cpart[2][HID];
  __shared__ f32x4 redbuf[8][64];

  const int g    = blockIdx.x;
  const int t    = threadIdx.x;
  const int lane = t & 63;
  const int w    = t >> 6;
  const int b    = dsid[g];
  const int l15  = lane & 15;
  const int l4   = lane >> 4;

  // ---- stage x fp32 -> bf16 LDS tile, accumulate column sums (for mean pool) ----
  {
    const int cq   = (t & 127) * 4;   // column quad
    const int half = t >> 7;          // even/odd rows
    float cs0 = 0.f, cs1 = 0.f, cs2 = 0.f, cs3 = 0.f;
    const float* xbase = x + (size_t)g * NPG * HID;
    #pragma unroll
    for (int i = 0; i < 16; ++i) {
      int row = half + i * 2;
      float4 v = *(const float4*)(xbase + row * HID + cq);
      cs0 += v.x; cs1 += v.y; cs2 += v.z; cs3 += v.w;
      ushort4 u;
      u.x = f2bf(v.x); u.y = f2bf(v.y); u.z = f2bf(v.z); u.w = f2bf(v.w);
      *(ushort4*)&tile[row * LDH + cq] = u;
    }
    float4 cv; cv.x = cs0; cv.y = cs1; cv.z = cs2; cv.w = cs3;
    *(float4*)&cpart[half][cq] = cv;
  }
  __syncthreads();

  // ---- graph mean side-output (bf16) ----
  {
    int c = t * 2;
    float m0 = (cpart[0][c] + cpart[1][c]) * (1.f / 32.f);
    float m1 = (cpart[0][c + 1] + cpart[1][c + 1]) * (1.f / 32.f);
    unsigned int packed = (unsigned int)f2bf(m0) | ((unsigned int)f2bf(m1) << 16);
    *(unsigned int*)&xg[(size_t)g * HID + c] = packed;
  }

  // ---- stage 1: h = relu(x @ Wn1[b] + bn1[b]); each wave owns 128 h-columns ----
  f32x4 acc[2][8];
  #pragma unroll
  for (int m = 0; m < 2; ++m)
    #pragma unroll
    for (int n = 0; n < 8; ++n) acc[m][n] = (f32x4)0.f;

  const int aoff0 = l15 * LDH + l4 * 8;
  const unsigned short* bbase =
      W1T + (size_t)(b * 512 + w * 128 + l15) * 512 + l4 * 8;

  for (int ks = 0; ks < 16; ++ks) {
    bf16x8 a0 = *(const bf16x8*)&tile[aoff0 + ks * 32];
    bf16x8 a1 = *(const bf16x8*)&tile[aoff0 + 16 * LDH + ks * 32];
    #pragma unroll
    for (int n = 0; n < 8; ++n) {
      bf16x8 bb = *(const bf16x8*)(bbase + n * 16 * 512 + ks * 32);
      acc[0][n] = mfma_bf16(a0, bb, acc[0][n]);
      acc[1][n] = mfma_bf16(a1, bb, acc[1][n]);
    }
  }
  __syncthreads();  // everyone finished reading the x tile

  // bias + relu -> bf16 h back into the same tile (each wave writes its own cols)
  #pragma unroll
  for (int n = 0; n < 8; ++n) {
    int col = w * 128 + n * 16 + l15;
    float bias = bn1[b * HID + col];
    #pragma unroll
    for (int m = 0; m < 2; ++m) {
      #pragma unroll
      for (int r = 0; r < 4; ++r) {
        float v = fmaxf(acc[m][n][r] + bias, 0.f);
        tile[(m * 16 + l4 * 4 + r) * LDH + col] = f2bf(v);
      }
    }
  }
  // stage 2 reads only this wave's own columns -> no barrier needed here.

  // ---- stage 2: on = h @ Wn2[b] (N padded to 16, K split across the 4 waves) ----
  f32x4 acc2[2];
  acc2[0] = (f32x4)0.f; acc2[1] = (f32x4)0.f;
  const unsigned short* b2 =
      W2T + (size_t)(b * 16 + l15) * 512 + w * 128 + l4 * 8;
  #pragma unroll
  for (int kk = 0; kk < 4; ++kk) {
    bf16x8 a0 = *(const bf16x8*)&tile[aoff0 + w * 128 + kk * 32];
    bf16x8 a1 = *(const bf16x8*)&tile[aoff0 + 16 * LDH + w * 128 + kk * 32];
    bf16x8 bb = *(const bf16x8*)(b2 + kk * 32);
    acc2[0] = mfma_bf16(a0, bb, acc2[0]);
    acc2[1] = mfma_bf16(a1, bb, acc2[1]);
  }
  redbuf[w * 2 + 0][lane] = acc2[0];
  redbuf[w * 2 + 1][lane] = acc2[1];
  __syncthreads();

  if (t < 128) {
    int m = t >> 6;
    int ln = t & 63;
    f32x4 s = redbuf[m][ln] + redbuf[2 + m][ln] + redbuf[4 + m][ln] + redbuf[6 + m][ln];
    int j = ln & 15;
    if (j < 6) {
      float bias = bn2[b * 6 + j];
      int rbase = m * 16 + (ln >> 4) * 4;
      #pragma unroll
      for (int r = 0; r < 4; ++r) {
        float on = s[r] + bias;
        int node = g * NPG + rbase + r;
        if (j < 3) n_head[(size_t)node * 3 + j] = on;
        else       n_var[(size_t)node * 3 + (j - 3)] = on * on;
      }
    }
  }
}

// ---------------- graph MLP: 32 graphs/block, loop all 4 branches, masked write ----
__global__ __launch_bounds__(256, 2) void graph_kernel(
    const float* __restrict__ bs_,
    const float* __restrict__ bg,
    const int* __restrict__ dsid,
    const unsigned short* __restrict__ WsT,   // [b][512][512] bf16
    const unsigned short* __restrict__ WgT,   // [b][128][512] bf16 (rows 100..127 zero)
    const unsigned short* __restrict__ xg,    // [4096][512] bf16
    float* __restrict__ g_head,
    float* __restrict__ g_var) {
  __shared__ __align__(16) unsigned short xt[32 * LDH];
  __shared__ __align__(16) unsigned short ht[32 * LDH];

  const int g0   = blockIdx.x * 32;
  const int t    = threadIdx.x;
  const int lane = t & 63;
  const int w    = t >> 6;
  const int l15  = lane & 15;
  const int l4   = lane >> 4;
  const int aoff0 = l15 * LDH + l4 * 8;

  #pragma unroll
  for (int i = 0; i < 8; ++i) {
    int fid = t + i * 256;
    int row = fid >> 6;
    int col8 = (fid & 63) * 8;
    *(bf16x8*)&xt[row * LDH + col8] =
        *(const bf16x8*)&xg[(size_t)(g0 + row) * HID + col8];
  }
  __syncthreads();

  for (int b = 0; b < 4; ++b) {
    // stage 1: hg = relu(xg @ Ws[b] + bs[b])
    f32x4 acc[2][8];
    #pragma unroll
    for (int m = 0; m < 2; ++m)
      #pragma unroll
      for (int n = 0; n < 8; ++n) acc[m][n] = (f32x4)0.f;

    const unsigned short* bbase =
        WsT + (size_t)(b * 512 + w * 128 + l15) * 512 + l4 * 8;
    for (int ks = 0; ks < 16; ++ks) {
      bf16x8 a0 = *(const bf16x8*)&xt[aoff0 + ks * 32];
      bf16x8 a1 = *(const bf16x8*)&xt[aoff0 + 16 * LDH + ks * 32];
      #pragma unroll
      for (int n = 0; n < 8; ++n) {
        bf16x8 bb = *(const bf16x8*)(bbase + n * 16 * 512 + ks * 32);
        acc[0][n] = mfma_bf16(a0, bb, acc[0][n]);
        acc[1][n] = mfma_bf16(a1, bb, acc[1][n]);
      }
    }
    __syncthreads();  // previous branch's stage-2 readers done before ht overwrite
    #pragma unroll
    for (int n = 0; n < 8; ++n) {
      int col = w * 128 + n * 16 + l15;
      float bias = bs_[b * HID + col];
      #pragma unroll
      for (int m = 0; m < 2; ++m) {
        #pragma unroll
        for (int r = 0; r < 4; ++r) {
          float v = fmaxf(acc[m][n][r] + bias, 0.f);
          ht[(m * 16 + l4 * 4 + r) * LDH + col] = f2bf(v);
        }
      }
    }
    __syncthreads();

    // stage 2: og = hg @ Wg[b] (N padded to 128; wave w owns cols [w*32, w*32+32))
    f32x4 acc2[2][2];
    #pragma unroll
    for (int m = 0; m < 2; ++m) { acc2[m][0] = (f32x4)0.f; acc2[m][1] = (f32x4)0.f; }
    const unsigned short* b2base =
        WgT + (size_t)(b * 128 + w * 32 + l15) * 512 + l4 * 8;
    for (int ks = 0; ks < 16; ++ks) {
      bf16x8 a0 = *(const bf16x8*)&ht[aoff0 + ks * 32];
      bf16x8 a1 = *(const bf16x8*)&ht[aoff0 + 16 * LDH + ks * 32];
      #pragma unroll
      for (int n2 = 0; n2 < 2; ++n2) {
        bf16x8 bb = *(const bf16x8*)(b2base + n2 * 16 * 512 + ks * 32);
        acc2[0][n2] = mfma_bf16(a0, bb, acc2[0][n2]);
        acc2[1][n2] = mfma_bf16(a1, bb, acc2[1][n2]);
      }
    }
    #pragma unroll
    for (int n2 = 0; n2 < 2; ++n2) {
      int jj = w * 32 + n2 * 16 + l15;
      if (jj < 100) {
        float bias = bg[b * 100 + jj];
        #pragma unroll
        for (int m = 0; m < 2; ++m) {
          #pragma unroll
          for (int r = 0; r < 4; ++r) {
            int row = m * 16 + l4 * 4 + r;
            if (dsid[g0 + row] == b) {
              float og = acc2[m][n2][r] + bias;
              if (jj < 50) g_head[(size_t)(g0 + row) * 50 + jj] = og;
              else         g_var[(size_t)(g0 + row) * 50 + (jj - 50)] = og * og;
            }
          }
        }
      }
    }
    // ht protected by the first __syncthreads() of the next branch iteration
  }
}

extern "C" void kernel_launch(void* const* d_in, const int* in_sizes, int n_in,
                              void* d_out, int out_size, void* d_ws, size_t ws_size,
                              hipStream_t stream) {
  const float* x    = (const float*)d_in[0];
  const float* Ws   = (const float*)d_in[1];
  const float* bs   = (const float*)d_in[2];
  const float* Wg   = (const float*)d_in[3];
  const float* bg   = (const float*)d_in[4];
  const float* Wn1  = (const float*)d_in[5];
  const float* bn1  = (const float*)d_in[6];
  const float* Wn2  = (const float*)d_in[7];
  const float* bn2  = (const float*)d_in[8];
  // d_in[9] = batch: structure known (32 consecutive nodes per graph), unused
  const int* dsid   = (const int*)d_in[10];

  float* out    = (float*)d_out;
  float* g_head = out;                                  // 4096*50
  float* g_var  = out + (size_t)N_GRAPHS * 50;          // 4096*50
  float* n_head = out + (size_t)2 * N_GRAPHS * 50;      // 131072*3
  float* n_var  = n_head + (size_t)N_NODES * 3;

  char* ws = (char*)d_ws;
  unsigned short* xg  = (unsigned short*)(ws);              // 4,194,304 B
  unsigned short* W1T = (unsigned short*)(ws + 4194304);    // 2,097,152 B
  unsigned short* WsT = (unsigned short*)(ws + 6291456);    // 2,097,152 B
  unsigned short* W2T = (unsigned short*)(ws + 8388608);    //    65,536 B
  unsigned short* WgT = (unsigned short*)(ws + 8454144);    //   524,288 B
  if (ws_size < 8978432) return;  // need ~9 MB scratch

  prep_t512_kernel<<<dim3(2048), dim3(256), 0, stream>>>(Wn1, Ws, W1T, WsT);
  prep_small_kernel<<<dim3(1152), dim3(256), 0, stream>>>(Wn2, Wg, W2T, WgT);
  node_kernel<<<dim3(N_GRAPHS), dim3(256), 0, stream>>>(
      x, bn1, bn2, dsid, W1T, W2T, xg, n_head, n_var);
  graph_kernel<<<dim3(N_GRAPHS / 32), dim3(256), 0, stream>>>(
      bs, bg, dsid, WsT, WgT, xg, g_head, g_var);
}

// Round 2
// 284.857 us; speedup vs baseline: 1.7696x; 1.7696x over previous
//
#include <hip/hip_runtime.h>

#define N_NODES  131072
#define N_GRAPHS 4096
#define HID      512

typedef float  f32x4  __attribute__((ext_vector_type(4)));
typedef __bf16 bf16x8 __attribute__((ext_vector_type(8)));
typedef unsigned short u16x8 __attribute__((ext_vector_type(8)));

__device__ __forceinline__ unsigned short f2bf(float f) {
  unsigned int u = __builtin_bit_cast(unsigned int, f);
  u += 0x7FFFu + ((u >> 16) & 1u);   // round-to-nearest-even
  return (unsigned short)(u >> 16);
}

__device__ __forceinline__ f32x4 mfma_bf16(bf16x8 a, bf16x8 b, f32x4 c) {
  return __builtin_amdgcn_mfma_f32_16x16x32_bf16(a, b, c, 0, 0, 0);
}

// ---------- bucket: sort graphs by branch ----------
__global__ __launch_bounds__(256) void bucket_kernel(
    const int* __restrict__ dsid, int* __restrict__ perm, int* __restrict__ meta) {
  __shared__ int cnt[4], base[4], off[4];
  int t = threadIdx.x;
  if (t < 4) { cnt[t] = 0; off[t] = 0; }
  __syncthreads();
  for (int g = t; g < N_GRAPHS; g += 256) atomicAdd(&cnt[dsid[g]], 1);
  __syncthreads();
  if (t == 0) {
    int s = 0;
    for (int b = 0; b < 4; ++b) { base[b] = s; s += cnt[b]; meta[b] = cnt[b]; }
  }
  __syncthreads();
  for (int g = t; g < N_GRAPHS; g += 256) {
    int b = dsid[g];
    int p = base[b] + atomicAdd(&off[b], 1);
    perm[p] = g;
  }
}

// ---------- pool: per-graph mean of 32 rows (fp32 accurate) -> xg bf16 ----------
__global__ __launch_bounds__(256) void pool_kernel(
    const float* __restrict__ x, unsigned short* __restrict__ xg) {
  __shared__ float cpart[2][HID];
  const int g = blockIdx.x;
  const int t = threadIdx.x;
  const int cq   = (t & 127) * 4;
  const int half = t >> 7;
  float cs0 = 0.f, cs1 = 0.f, cs2 = 0.f, cs3 = 0.f;
  const float* xbase = x + (size_t)g * 32 * HID;
  #pragma unroll
  for (int i = 0; i < 16; ++i) {
    int row = half + i * 2;
    float4 v = *(const float4*)(xbase + row * HID + cq);
    cs0 += v.x; cs1 += v.y; cs2 += v.z; cs3 += v.w;
  }
  float4 cv; cv.x = cs0; cv.y = cs1; cv.z = cs2; cv.w = cs3;
  *(float4*)&cpart[half][cq] = cv;
  __syncthreads();
  int c = t * 2;
  float m0 = (cpart[0][c] + cpart[1][c]) * (1.f / 32.f);
  float m1 = (cpart[0][c + 1] + cpart[1][c + 1]) * (1.f / 32.f);
  unsigned int packed = (unsigned int)f2bf(m0) | ((unsigned int)f2bf(m1) << 16);
  *(unsigned int*)&xg[(size_t)g * HID + c] = packed;
}

// ---------- prep: W[b][k][n] fp32 -> WT[b][n][k] bf16 (Wn1 & Ws) ----------
__global__ __launch_bounds__(256) void prep_t512_kernel(
    const float* __restrict__ Wn1, const float* __restrict__ Ws,
    unsigned short* __restrict__ W1T, unsigned short* __restrict__ WsT) {
  __shared__ unsigned short lt[32][33];
  const int bid = blockIdx.x;          // 2048 blocks
  const int which = bid >> 10;
  const int b  = (bid >> 8) & 3;
  const int ti = (bid >> 4) & 15;
  const int tj = bid & 15;
  const float* src = which ? Ws : Wn1;
  unsigned short* dst = which ? WsT : W1T;
  const int t = threadIdx.x;
  const int c = t & 31;
  const int r0 = (t >> 5) * 4;
  #pragma unroll
  for (int rr = 0; rr < 4; ++rr) {
    int row = r0 + rr;
    lt[row][c] = f2bf(src[(b * 512 + ti * 32 + row) * 512 + tj * 32 + c]);
  }
  __syncthreads();
  #pragma unroll
  for (int rr = 0; rr < 4; ++rr) {
    int row = r0 + rr;
    dst[(b * 512 + tj * 32 + row) * 512 + ti * 32 + c] = lt[c][row];
  }
}

// ---------- prep: Wg (4,512,100) -> WgT [b][128][512] bf16 zero-pad ----------
__global__ __launch_bounds__(256) void prep_wg_kernel(
    const float* __restrict__ Wg, unsigned short* __restrict__ WgT) {
  int idx = blockIdx.x * 256 + threadIdx.x;   // 1024 blocks
  int b = idx >> 16;
  int r = (idx >> 9) & 127;
  int k = idx & 511;
  float v = (r < 100) ? Wg[(b * 512 + k) * 100 + r] : 0.f;
  WgT[idx] = f2bf(v);
}

// ---------- unified stage-1 (+fused node stage-2) ----------
// Node tiles: 64 node rows (2 graphs, uniform branch). Graph tiles: 64 pooled rows.
// Swapped MFMA: D^T = A(W^T) x B(rows): C lane layout: nodecol=l15, hcolrow=4*l4+r.
#define NT_MAX 2050
#define GT_MAX 67
__global__ __launch_bounds__(256, 2) void unified_kernel(
    const float* __restrict__ x,
    const unsigned short* __restrict__ xg,
    const int* __restrict__ meta,
    const int* __restrict__ perm,
    const unsigned short* __restrict__ W1T,
    const unsigned short* __restrict__ WsT,
    const float* __restrict__ bn1,
    const float* __restrict__ bs_,
    const float* __restrict__ Wn2,
    const float* __restrict__ bn2,
    unsigned short* __restrict__ hg,
    float* __restrict__ n_head,
    float* __restrict__ n_var) {
  __shared__ __align__(16) unsigned short sbuf[2][64 * 64];  // 2 x 8KB, swizzled
  __shared__ float bias1[HID];
  __shared__ float W2f[HID * 6];
  __shared__ int   gidl[64];
  __shared__ __align__(16) float red[4][64][6];

  const int4 cv = *(const int4*)meta;
  const int cnts[4] = {cv.x, cv.y, cv.z, cv.w};

  int bid = blockIdx.x;
  bool isNode;
  int branch = -1, permOff = 0, nvalid = 0;
  if (bid < NT_MAX) {
    isNode = true;
    int i = bid, pb = 0;
    for (int b = 0; b < 4; ++b) {
      int nt = (cnts[b] + 1) >> 1;
      if (branch < 0 && i < nt) { branch = b; permOff = pb + i * 2; nvalid = min(2, cnts[b] - i * 2); }
      if (branch < 0) i -= nt;
      pb += cnts[b];
    }
    if (branch < 0) return;
  } else {
    isNode = false;
    int i = bid - NT_MAX, pb = 0;
    for (int b = 0; b < 4; ++b) {
      int gt = (cnts[b] + 63) >> 6;
      if (branch < 0 && i < gt) { branch = b; permOff = pb + i * 64; nvalid = min(64, cnts[b] - i * 64); }
      if (branch < 0) i -= gt;
      pb += cnts[b];
    }
    if (branch < 0) return;
  }

  const int t    = threadIdx.x;
  const int lane = t & 63;
  const int w    = t >> 6;        // wave id: hcol chunk (w*128)
  const int l15  = lane & 15;
  const int l4   = lane >> 4;

  // ---- setup LDS ----
  if (t < 64) gidl[t] = perm[permOff + min(t, nvalid - 1)];
  {
    const float* bsrc = (isNode ? bn1 : bs_) + branch * HID;
    bias1[t] = bsrc[t];
    bias1[t + 256] = bsrc[t + 256];
  }
  if (isNode) {
    const float* wsrc = Wn2 + branch * HID * 6;
    for (int i = t; i < HID * 6; i += 256) W2f[i] = wsrc[i];
  }
  __syncthreads();

  const unsigned short* WT = (isNode ? W1T : WsT);
  const unsigned short* wb = WT + ((size_t)branch * 512 + w * 128 + l15) * 512 + l4 * 8;

  // staging geometry: thread -> (srow 0..63, 16-elem chunk)
  const int srow   = t >> 2;
  const int schunk = (t & 3) * 16;
  const int slot0  = ((schunk >> 3) ^ (srow & 7));
  const int slot1  = (((schunk >> 3) + 1) ^ (srow & 7));
  const int wr0 = srow * 64 + slot0 * 8;
  const int wr1 = srow * 64 + slot1 * 8;

  f32x4 acc[8][4];
  #pragma unroll
  for (int m = 0; m < 8; ++m)
    #pragma unroll
    for (int n = 0; n < 4; ++n) acc[m][n] = (f32x4)0.f;

  // ---- prologue: stage ks=0 ----
  float4 st0, st1, st2, st3;
  u16x8 sg0, sg1;
  if (isNode) {
    int g = gidl[srow >> 5];
    const float* src = x + ((size_t)g * 32 + (srow & 31)) * HID + schunk;
    st0 = *(const float4*)(src);     st1 = *(const float4*)(src + 4);
    st2 = *(const float4*)(src + 8); st3 = *(const float4*)(src + 12);
    u16x8 lo, hi;
    lo[0]=f2bf(st0.x); lo[1]=f2bf(st0.y); lo[2]=f2bf(st0.z); lo[3]=f2bf(st0.w);
    lo[4]=f2bf(st1.x); lo[5]=f2bf(st1.y); lo[6]=f2bf(st1.z); lo[7]=f2bf(st1.w);
    hi[0]=f2bf(st2.x); hi[1]=f2bf(st2.y); hi[2]=f2bf(st2.z); hi[3]=f2bf(st2.w);
    hi[4]=f2bf(st3.x); hi[5]=f2bf(st3.y); hi[6]=f2bf(st3.z); hi[7]=f2bf(st3.w);
    *(u16x8*)&sbuf[0][wr0] = lo;
    *(u16x8*)&sbuf[0][wr1] = hi;
  } else {
    int g = gidl[srow];
    const unsigned short* src = xg + (size_t)g * HID + schunk;
    sg0 = *(const u16x8*)(src);
    sg1 = *(const u16x8*)(src + 8);
    *(u16x8*)&sbuf[0][wr0] = sg0;
    *(u16x8*)&sbuf[0][wr1] = sg1;
  }
  __syncthreads();

  // ---- K loop: 8 steps of BK=64 ----
  for (int ks = 0; ks < 8; ++ks) {
    // prefetch next stage into regs
    if (ks < 7) {
      if (isNode) {
        int g = gidl[srow >> 5];
        const float* src = x + ((size_t)g * 32 + (srow & 31)) * HID + (ks + 1) * 64 + schunk;
        st0 = *(const float4*)(src);     st1 = *(const float4*)(src + 4);
        st2 = *(const float4*)(src + 8); st3 = *(const float4*)(src + 12);
      } else {
        int g = gidl[srow];
        const unsigned short* src = xg + (size_t)g * HID + (ks + 1) * 64 + schunk;
        sg0 = *(const u16x8*)(src);
        sg1 = *(const u16x8*)(src + 8);
      }
    }
    // compute on current buffer
    const unsigned short* cur = sbuf[ks & 1];
    #pragma unroll
    for (int kk = 0; kk < 2; ++kk) {
      bf16x8 af[8];
      #pragma unroll
      for (int m = 0; m < 8; ++m)
        af[m] = *(const bf16x8*)(wb + (size_t)m * 16 * 512 + ks * 64 + kk * 32);
      bf16x8 bfr[4];
      #pragma unroll
      for (int n = 0; n < 4; ++n) {
        int row = n * 16 + l15;
        int slot = ((kk * 4 + l4) ^ (row & 7));
        bfr[n] = *(const bf16x8*)(cur + row * 64 + slot * 8);
      }
      #pragma unroll
      for (int m = 0; m < 8; ++m)
        #pragma unroll
        for (int n = 0; n < 4; ++n)
          acc[m][n] = mfma_bf16(af[m], bfr[n], acc[m][n]);
    }
    // write next buffer
    if (ks < 7) {
      unsigned short* nb = sbuf[(ks + 1) & 1];
      if (isNode) {
        u16x8 lo, hi;
        lo[0]=f2bf(st0.x); lo[1]=f2bf(st0.y); lo[2]=f2bf(st0.z); lo[3]=f2bf(st0.w);
        lo[4]=f2bf(st1.x); lo[5]=f2bf(st1.y); lo[6]=f2bf(st1.z); lo[7]=f2bf(st1.w);
        hi[0]=f2bf(st2.x); hi[1]=f2bf(st2.y); hi[2]=f2bf(st2.z); hi[3]=f2bf(st2.w);
        hi[4]=f2bf(st3.x); hi[5]=f2bf(st3.y); hi[6]=f2bf(st3.z); hi[7]=f2bf(st3.w);
        *(u16x8*)&nb[wr0] = lo;
        *(u16x8*)&nb[wr1] = hi;
      } else {
        *(u16x8*)&nb[wr0] = sg0;
        *(u16x8*)&nb[wr1] = sg1;
      }
      __syncthreads();
    }
  }

  // ---- epilogue ----
  if (isNode) {
    // fused stage-2: on = relu(h) @ Wn2 + bn2, per-lane VALU over its 32 hcols
    float part[4][6];
    #pragma unroll
    for (int n = 0; n < 4; ++n)
      #pragma unroll
      for (int j = 0; j < 6; ++j) part[n][j] = 0.f;
    #pragma unroll
    for (int m = 0; m < 8; ++m) {
      #pragma unroll
      for (int r = 0; r < 4; ++r) {
        int hcol = w * 128 + m * 16 + l4 * 4 + r;
        float b1 = bias1[hcol];
        float w2[6];
        #pragma unroll
        for (int j = 0; j < 6; ++j) w2[j] = W2f[hcol * 6 + j];
        #pragma unroll
        for (int n = 0; n < 4; ++n) {
          float h = fmaxf(acc[m][n][r] + b1, 0.f);
          #pragma unroll
          for (int j = 0; j < 6; ++j) part[n][j] += h * w2[j];
        }
      }
    }
    #pragma unroll
    for (int n = 0; n < 4; ++n)
      #pragma unroll
      for (int j = 0; j < 6; ++j) {
        part[n][j] += __shfl_xor(part[n][j], 16);
        part[n][j] += __shfl_xor(part[n][j], 32);
      }
    if (lane < 16) {
      #pragma unroll
      for (int n = 0; n < 4; ++n)
        #pragma unroll
        for (int j = 0; j < 6; ++j) red[w][n * 16 + l15][j] = part[n][j];
    }
    __syncthreads();
    if (t < 64) {
      int row = t;
      if (row < nvalid * 32) {
        int node = gidl[row >> 5] * 32 + (row & 31);
        #pragma unroll
        for (int j = 0; j < 6; ++j) {
          float s = red[0][row][j] + red[1][row][j] + red[2][row][j] + red[3][row][j]
                    + bn2[branch * 6 + j];
          if (j < 3) n_head[(size_t)node * 3 + j] = s;
          else       n_var[(size_t)node * 3 + (j - 3)] = s * s;
        }
      }
    }
  } else {
    // graph tile: write hg = relu(acc + bs[branch]) bf16, scattered by graph id
    #pragma unroll
    for (int m = 0; m < 8; ++m) {
      #pragma unroll
      for (int n = 0; n < 4; ++n) {
        int row = n * 16 + l15;
        if (row < nvalid) {
          int g = gidl[row];
          int hcb = w * 128 + m * 16 + l4 * 4;
          ushort4 hv;
          hv.x = f2bf(fmaxf(acc[m][n][0] + bias1[hcb + 0], 0.f));
          hv.y = f2bf(fmaxf(acc[m][n][1] + bias1[hcb + 1], 0.f));
          hv.z = f2bf(fmaxf(acc[m][n][2] + bias1[hcb + 2], 0.f));
          hv.w = f2bf(fmaxf(acc[m][n][3] + bias1[hcb + 3], 0.f));
          *(ushort4*)(hg + (size_t)g * HID + hcb) = hv;
        }
      }
    }
  }
}

// ---------- graph stage-2: og = hg @ Wg[b] + bg, 16 graphs/block, branch-uniform ----------
#define G2_MAX 259
__global__ __launch_bounds__(256) void gstage2_kernel(
    const int* __restrict__ meta,
    const int* __restrict__ perm,
    const unsigned short* __restrict__ hg,
    const unsigned short* __restrict__ WgT,
    const float* __restrict__ bg,
    float* __restrict__ g_head,
    float* __restrict__ g_var) {
  __shared__ int gidl[16];
  const int4 cv = *(const int4*)meta;
  const int cnts[4] = {cv.x, cv.y, cv.z, cv.w};

  int i = blockIdx.x, branch = -1, permOff = 0, nvalid = 0, pb = 0;
  for (int b = 0; b < 4; ++b) {
    int gt = (cnts[b] + 15) >> 4;
    if (branch < 0 && i < gt) { branch = b; permOff = pb + i * 16; nvalid = min(16, cnts[b] - i * 16); }
    if (branch < 0) i -= gt;
    pb += cnts[b];
  }
  if (branch < 0) return;

  const int t    = threadIdx.x;
  const int lane = t & 63;
  const int w    = t >> 6;
  const int l15  = lane & 15;
  const int l4   = lane >> 4;

  if (t < 16) gidl[t] = perm[permOff + min(t, nvalid - 1)];
  __syncthreads();

  f32x4 acc2[2];
  acc2[0] = (f32x4)0.f; acc2[1] = (f32x4)0.f;
  const unsigned short* arow = hg + (size_t)gidl[l15] * HID + l4 * 8;
  const unsigned short* brow = WgT + ((size_t)branch * 128 + w * 32 + l15) * 512 + l4 * 8;
  #pragma unroll
  for (int ks = 0; ks < 16; ++ks) {
    bf16x8 a  = *(const bf16x8*)(arow + ks * 32);
    bf16x8 b0 = *(const bf16x8*)(brow + ks * 32);
    bf16x8 b1 = *(const bf16x8*)(brow + 16 * 512 + ks * 32);
    acc2[0] = mfma_bf16(a, b0, acc2[0]);
    acc2[1] = mfma_bf16(a, b1, acc2[1]);
  }
  #pragma unroll
  for (int n2 = 0; n2 < 2; ++n2) {
    int j = w * 32 + n2 * 16 + l15;
    if (j < 100) {
      float bias = bg[branch * 100 + j];
      #pragma unroll
      for (int rr = 0; rr < 4; ++rr) {
        int r = l4 * 4 + rr;
        if (r < nvalid) {
          int g = gidl[r];
          float val = acc2[n2][rr] + bias;
          if (j < 50) g_head[(size_t)g * 50 + j] = val;
          else        g_var[(size_t)g * 50 + (j - 50)] = val * val;
        }
      }
    }
  }
}

extern "C" void kernel_launch(void* const* d_in, const int* in_sizes, int n_in,
                              void* d_out, int out_size, void* d_ws, size_t ws_size,
                              hipStream_t stream) {
  const float* x    = (const float*)d_in[0];
  const float* Ws   = (const float*)d_in[1];
  const float* bs   = (const float*)d_in[2];
  const float* Wg   = (const float*)d_in[3];
  const float* bg   = (const float*)d_in[4];
  const float* Wn1  = (const float*)d_in[5];
  const float* bn1  = (const float*)d_in[6];
  const float* Wn2  = (const float*)d_in[7];
  const float* bn2  = (const float*)d_in[8];
  const int* dsid   = (const int*)d_in[10];

  float* out    = (float*)d_out;
  float* g_head = out;
  float* g_var  = out + (size_t)N_GRAPHS * 50;
  float* n_head = out + (size_t)2 * N_GRAPHS * 50;
  float* n_var  = n_head + (size_t)N_NODES * 3;

  char* ws = (char*)d_ws;
  int* perm = (int*)(ws);                                   // 16384
  int* meta = (int*)(ws + 16384);                           // 256
  unsigned short* W1T = (unsigned short*)(ws + 16640);      // 2,097,152
  unsigned short* WsT = (unsigned short*)(ws + 2113792);    // 2,097,152
  unsigned short* WgT = (unsigned short*)(ws + 4210944);    // 524,288
  unsigned short* xg  = (unsigned short*)(ws + 4735232);    // 4,194,304
  unsigned short* hg  = (unsigned short*)(ws + 8929536);    // 4,194,304
  if (ws_size < 13123840) return;

  bucket_kernel<<<dim3(1), dim3(256), 0, stream>>>(dsid, perm, meta);
  pool_kernel<<<dim3(N_GRAPHS), dim3(256), 0, stream>>>(x, xg);
  prep_t512_kernel<<<dim3(2048), dim3(256), 0, stream>>>(Wn1, Ws, W1T, WsT);
  prep_wg_kernel<<<dim3(1024), dim3(256), 0, stream>>>(Wg, WgT);
  unified_kernel<<<dim3(NT_MAX + GT_MAX), dim3(256), 0, stream>>>(
      x, xg, meta, perm, W1T, WsT, bn1, bs, Wn2, bn2, hg, n_head, n_var);
  gstage2_kernel<<<dim3(G2_MAX), dim3(256), 0, stream>>>(
      meta, perm, hg, WgT, bg, g_head, g_var);
}

// Round 3
// 196.902 us; speedup vs baseline: 2.5601x; 1.4467x over previous
//
#include <hip/hip_runtime.h>

#define N_NODES  131072
#define N_GRAPHS 4096
#define HID      512

typedef float  f32x4  __attribute__((ext_vector_type(4)));
typedef __bf16 bf16x8 __attribute__((ext_vector_type(8)));
typedef unsigned short u16x8 __attribute__((ext_vector_type(8)));

__device__ __forceinline__ unsigned short f2bf(float f) {
  unsigned int u = __builtin_bit_cast(unsigned int, f);
  u += 0x7FFFu + ((u >> 16) & 1u);   // round-to-nearest-even
  return (unsigned short)(u >> 16);
}
__device__ __forceinline__ unsigned int pack2bf(float a, float b) {
  return (unsigned int)f2bf(a) | ((unsigned int)f2bf(b) << 16);
}
__device__ __forceinline__ f32x4 mfma_bf16(bf16x8 a, bf16x8 b, f32x4 c) {
  return __builtin_amdgcn_mfma_f32_16x16x32_bf16(a, b, c, 0, 0, 0);
}

// ---------- bucket: sort graphs by branch ----------
__global__ __launch_bounds__(256) void bucket_kernel(
    const int* __restrict__ dsid, int* __restrict__ perm, int* __restrict__ meta) {
  __shared__ int cnt[4], base[4], off[4];
  int t = threadIdx.x;
  if (t < 4) { cnt[t] = 0; off[t] = 0; }
  __syncthreads();
  for (int g = t; g < N_GRAPHS; g += 256) atomicAdd(&cnt[dsid[g]], 1);
  __syncthreads();
  if (t == 0) {
    int s = 0;
    for (int b = 0; b < 4; ++b) { base[b] = s; s += cnt[b]; meta[b] = cnt[b]; }
  }
  __syncthreads();
  for (int g = t; g < N_GRAPHS; g += 256) {
    int b = dsid[g];
    int p = base[b] + atomicAdd(&off[b], 1);
    perm[p] = g;
  }
}

// ---------- prep: W[b][k][n] fp32 -> fragment-ordered bf16 -------------------
// Layout: [b][hf=32][kk=16][lane=64][e=8]; value = W[k=kk*32+(lane>>4)*8+e][n=hf*16+(lane&15)]
__global__ __launch_bounds__(256) void prep_wf_kernel(
    const float* __restrict__ Wn1, const float* __restrict__ Ws,
    unsigned short* __restrict__ W1Tf, unsigned short* __restrict__ WsTf) {
  __shared__ unsigned short lt[8192];
  const int bid = blockIdx.x;          // 256 blocks
  const int which = bid >> 7;
  const int b  = (bid >> 5) & 3;
  const int hf = bid & 31;
  const float* src = (which ? Ws : Wn1) + (size_t)b * 512 * 512 + hf * 16;
  unsigned short* dst = (which ? WsTf : W1Tf) + (size_t)(b * 32 + hf) * 8192;
  const int t = threadIdx.x;
  for (int i = t; i < 8192; i += 256) {
    int k = i >> 4;
    int n = i & 15;
    float v = src[(size_t)k * 512 + n];
    int kk = k >> 5, lane = n + ((k >> 3) & 3) * 16, e = k & 7;
    lt[(kk * 64 + lane) * 8 + e] = f2bf(v);
  }
  __syncthreads();
  u16x8* d8 = (u16x8*)dst;
  const u16x8* s8 = (const u16x8*)lt;
  for (int i = t; i < 1024; i += 256) d8[i] = s8[i];
}

// ---------- prep: Wg (4,512,100) -> WgT [b][128][512] bf16 zero-pad ----------
__global__ __launch_bounds__(256) void prep_wg_kernel(
    const float* __restrict__ Wg, unsigned short* __restrict__ WgT) {
  int idx = blockIdx.x * 256 + threadIdx.x;   // 1024 blocks
  int b = idx >> 16;
  int r = (idx >> 9) & 127;
  int k = idx & 511;
  float v = (r < 100) ? Wg[(b * 512 + k) * 100 + r] : 0.f;
  WgT[idx] = f2bf(v);
}

// ---------- node kernel: pool + stage1 MFMA + fused stage2 -------------------
// 512 threads = 8 waves x 64 hcols. M=64 rows (2 graphs, branch-uniform).
// xtile fragment order: [nf=4][kk=16][lane=64][e=8] bf16 (64KB). No K-loop barriers.
#define NT_MAX 2050
__global__ __launch_bounds__(512, 4) void node_kernel(
    const float* __restrict__ x,
    const int* __restrict__ meta,
    const int* __restrict__ perm,
    const unsigned short* __restrict__ W1Tf,
    const float* __restrict__ bn1,
    const float* __restrict__ Wn2,
    const float* __restrict__ bn2,
    unsigned short* __restrict__ xg,
    float* __restrict__ n_head,
    float* __restrict__ n_var) {
  __shared__ __align__(16) unsigned short xtile[4 * 16 * 512];  // 65536 B
  __shared__ __align__(16) float red[8][64][6];                 // 12288 B

  const int4 cv = *(const int4*)meta;
  const int cnts[4] = {cv.x, cv.y, cv.z, cv.w};

  int i = blockIdx.x, branch = -1, permOff = 0, nvalid = 0, pb = 0;
  for (int b = 0; b < 4; ++b) {
    int nt = (cnts[b] + 1) >> 1;
    if (branch < 0 && i < nt) { branch = b; permOff = pb + i * 2; nvalid = min(2, cnts[b] - i * 2); }
    if (branch < 0) i -= nt;
    pb += cnts[b];
  }
  if (branch < 0) return;

  const int t    = threadIdx.x;
  const int lane = t & 63;
  const int w    = t >> 6;
  const int l15  = lane & 15;
  const int l4   = lane >> 4;

  const int g0 = perm[permOff];
  const int g1 = perm[permOff + (nvalid > 1 ? 1 : 0)];

  // ---- pool + stage: each thread owns 2 cols x 32 rows of one graph ----
  {
    const int gg = t >> 8;          // graph within tile
    const int ci = (t & 255) * 2;   // column pair
    const int g  = gg ? g1 : g0;
    const float* src = x + (size_t)g * 32 * HID + ci;
    const int kk = ci >> 5;
    const int ln = (ci >> 3) & 3;
    const int e  = ci & 7;
    float s0 = 0.f, s1 = 0.f;
    #pragma unroll 8
    for (int row = 0; row < 32; ++row) {
      float2 v = *(const float2*)(src + (size_t)row * HID);
      s0 += v.x; s1 += v.y;
      int rt = gg * 32 + row;
      int pos = (((rt >> 4) * 16 + kk) * 64 + ((rt & 15) + ln * 16)) * 8 + e;
      *(unsigned int*)&xtile[pos] = pack2bf(v.x, v.y);
    }
    if (gg == 0 || nvalid > 1)
      *(unsigned int*)&xg[(size_t)g * HID + ci] = pack2bf(s0 * (1.f / 32.f), s1 * (1.f / 32.f));
  }
  __syncthreads();

  // ---- stage 1: h^T fragments, K-loop with no barriers ----
  f32x4 acc[4][4];
  #pragma unroll
  for (int m = 0; m < 4; ++m)
    #pragma unroll
    for (int n = 0; n < 4; ++n) acc[m][n] = (f32x4)0.f;

  const unsigned short* wbase = W1Tf + ((size_t)(branch * 32 + w * 4)) * 8192 + lane * 8;
  const unsigned short* xbase = xtile + lane * 8;

  #pragma unroll
  for (int kk = 0; kk < 16; ++kk) {
    bf16x8 af[4];
    #pragma unroll
    for (int m = 0; m < 4; ++m)
      af[m] = *(const bf16x8*)(wbase + (m * 16 + kk) * 512);
    bf16x8 bfr[4];
    #pragma unroll
    for (int n = 0; n < 4; ++n)
      bfr[n] = *(const bf16x8*)(xbase + (n * 16 + kk) * 512);
    #pragma unroll
    for (int m = 0; m < 4; ++m)
      #pragma unroll
      for (int n = 0; n < 4; ++n)
        acc[m][n] = mfma_bf16(af[m], bfr[n], acc[m][n]);
  }

  // ---- fused stage 2: per-lane fp32 dot with Wn2 over this lane's 16 hcols ----
  float part[4][6];
  #pragma unroll
  for (int n = 0; n < 4; ++n)
    #pragma unroll
    for (int j = 0; j < 6; ++j) part[n][j] = 0.f;
  const float* W2 = Wn2 + branch * HID * 6;
  const float* B1 = bn1 + branch * HID;
  #pragma unroll
  for (int m = 0; m < 4; ++m) {
    #pragma unroll
    for (int r = 0; r < 4; ++r) {
      int hcol = w * 64 + m * 16 + l4 * 4 + r;
      float b1 = B1[hcol];
      float w2[6];
      #pragma unroll
      for (int j = 0; j < 6; ++j) w2[j] = W2[hcol * 6 + j];
      #pragma unroll
      for (int n = 0; n < 4; ++n) {
        float h = fmaxf(acc[m][n][r] + b1, 0.f);
        #pragma unroll
        for (int j = 0; j < 6; ++j) part[n][j] += h * w2[j];
      }
    }
  }
  #pragma unroll
  for (int n = 0; n < 4; ++n)
    #pragma unroll
    for (int j = 0; j < 6; ++j) {
      part[n][j] += __shfl_xor(part[n][j], 16);
      part[n][j] += __shfl_xor(part[n][j], 32);
    }
  if (lane < 16) {
    #pragma unroll
    for (int n = 0; n < 4; ++n)
      #pragma unroll
      for (int j = 0; j < 6; ++j) red[w][n * 16 + l15][j] = part[n][j];
  }
  __syncthreads();
  if (t < 64) {
    int row = t;
    if (row < nvalid * 32) {
      int node = (row < 32 ? g0 : g1) * 32 + (row & 31);
      #pragma unroll
      for (int j = 0; j < 6; ++j) {
        float s = red[0][row][j] + red[1][row][j] + red[2][row][j] + red[3][row][j]
                + red[4][row][j] + red[5][row][j] + red[6][row][j] + red[7][row][j]
                + bn2[branch * 6 + j];
        if (j < 3) n_head[(size_t)node * 3 + j] = s;
        else       n_var[(size_t)node * 3 + (j - 3)] = s * s;
      }
    }
  }
}

// ---------- graph stage-1: hg = relu(xg @ Ws + bs), 64 graphs/block ----------
#define GT_MAX 67
__global__ __launch_bounds__(512, 4) void gstage1_kernel(
    const unsigned short* __restrict__ xg,
    const int* __restrict__ meta,
    const int* __restrict__ perm,
    const unsigned short* __restrict__ WsTf,
    const float* __restrict__ bs_,
    unsigned short* __restrict__ hg) {
  __shared__ __align__(16) unsigned short xtile[4 * 16 * 512];
  __shared__ int gidl[64];

  const int4 cv = *(const int4*)meta;
  const int cnts[4] = {cv.x, cv.y, cv.z, cv.w};

  int i = blockIdx.x, branch = -1, permOff = 0, nvalid = 0, pb = 0;
  for (int b = 0; b < 4; ++b) {
    int gt = (cnts[b] + 63) >> 6;
    if (branch < 0 && i < gt) { branch = b; permOff = pb + i * 64; nvalid = min(64, cnts[b] - i * 64); }
    if (branch < 0) i -= gt;
    pb += cnts[b];
  }
  if (branch < 0) return;

  const int t    = threadIdx.x;
  const int lane = t & 63;
  const int w    = t >> 6;
  const int l15  = lane & 15;
  const int l4   = lane >> 4;

  if (t < 64) gidl[t] = perm[permOff + min(t, nvalid - 1)];
  __syncthreads();

  // stage xg rows -> fragment-ordered LDS (16B chunks)
  for (int idx = t; idx < 4096; idx += 512) {
    int row = idx >> 6;
    int c8  = (idx & 63) * 8;
    u16x8 v = *(const u16x8*)&xg[(size_t)gidl[row] * HID + c8];
    int kk = c8 >> 5, ln = (c8 >> 3) & 3;
    *(u16x8*)&xtile[(((row >> 4) * 16 + kk) * 64 + ((row & 15) + ln * 16)) * 8] = v;
  }
  __syncthreads();

  f32x4 acc[4][4];
  #pragma unroll
  for (int m = 0; m < 4; ++m)
    #pragma unroll
    for (int n = 0; n < 4; ++n) acc[m][n] = (f32x4)0.f;

  const unsigned short* wbase = WsTf + ((size_t)(branch * 32 + w * 4)) * 8192 + lane * 8;
  const unsigned short* xbase = xtile + lane * 8;
  #pragma unroll
  for (int kk = 0; kk < 16; ++kk) {
    bf16x8 af[4];
    #pragma unroll
    for (int m = 0; m < 4; ++m)
      af[m] = *(const bf16x8*)(wbase + (m * 16 + kk) * 512);
    bf16x8 bfr[4];
    #pragma unroll
    for (int n = 0; n < 4; ++n)
      bfr[n] = *(const bf16x8*)(xbase + (n * 16 + kk) * 512);
    #pragma unroll
    for (int m = 0; m < 4; ++m)
      #pragma unroll
      for (int n = 0; n < 4; ++n)
        acc[m][n] = mfma_bf16(af[m], bfr[n], acc[m][n]);
  }

  const float* B1 = bs_ + branch * HID;
  #pragma unroll
  for (int m = 0; m < 4; ++m) {
    #pragma unroll
    for (int n = 0; n < 4; ++n) {
      int row = n * 16 + l15;
      if (row < nvalid) {
        int g = gidl[row];
        int hcb = w * 64 + m * 16 + l4 * 4;
        ushort4 hv;
        hv.x = f2bf(fmaxf(acc[m][n][0] + B1[hcb + 0], 0.f));
        hv.y = f2bf(fmaxf(acc[m][n][1] + B1[hcb + 1], 0.f));
        hv.z = f2bf(fmaxf(acc[m][n][2] + B1[hcb + 2], 0.f));
        hv.w = f2bf(fmaxf(acc[m][n][3] + B1[hcb + 3], 0.f));
        *(ushort4*)(hg + (size_t)g * HID + hcb) = hv;
      }
    }
  }
}

// ---------- graph stage-2: og = hg @ Wg[b] + bg, 16 graphs/block -------------
#define G2_MAX 259
__global__ __launch_bounds__(256) void gstage2_kernel(
    const int* __restrict__ meta,
    const int* __restrict__ perm,
    const unsigned short* __restrict__ hg,
    const unsigned short* __restrict__ WgT,
    const float* __restrict__ bg,
    float* __restrict__ g_head,
    float* __restrict__ g_var) {
  __shared__ int gidl[16];
  const int4 cv = *(const int4*)meta;
  const int cnts[4] = {cv.x, cv.y, cv.z, cv.w};

  int i = blockIdx.x, branch = -1, permOff = 0, nvalid = 0, pb = 0;
  for (int b = 0; b < 4; ++b) {
    int gt = (cnts[b] + 15) >> 4;
    if (branch < 0 && i < gt) { branch = b; permOff = pb + i * 16; nvalid = min(16, cnts[b] - i * 16); }
    if (branch < 0) i -= gt;
    pb += cnts[b];
  }
  if (branch < 0) return;

  const int t    = threadIdx.x;
  const int lane = t & 63;
  const int w    = t >> 6;
  const int l15  = lane & 15;
  const int l4   = lane >> 4;

  if (t < 16) gidl[t] = perm[permOff + min(t, nvalid - 1)];
  __syncthreads();

  f32x4 acc2[2];
  acc2[0] = (f32x4)0.f; acc2[1] = (f32x4)0.f;
  const unsigned short* arow = hg + (size_t)gidl[l15] * HID + l4 * 8;
  const unsigned short* brow = WgT + ((size_t)branch * 128 + w * 32 + l15) * 512 + l4 * 8;
  #pragma unroll
  for (int ks = 0; ks < 16; ++ks) {
    bf16x8 a  = *(const bf16x8*)(arow + ks * 32);
    bf16x8 b0 = *(const bf16x8*)(brow + ks * 32);
    bf16x8 b1 = *(const bf16x8*)(brow + 16 * 512 + ks * 32);
    acc2[0] = mfma_bf16(a, b0, acc2[0]);
    acc2[1] = mfma_bf16(a, b1, acc2[1]);
  }
  #pragma unroll
  for (int n2 = 0; n2 < 2; ++n2) {
    int j = w * 32 + n2 * 16 + l15;
    if (j < 100) {
      float bias = bg[branch * 100 + j];
      #pragma unroll
      for (int rr = 0; rr < 4; ++rr) {
        int r = l4 * 4 + rr;
        if (r < nvalid) {
          int g = gidl[r];
          float val = acc2[n2][rr] + bias;
          if (j < 50) g_head[(size_t)g * 50 + j] = val;
          else        g_var[(size_t)g * 50 + (j - 50)] = val * val;
        }
      }
    }
  }
}

extern "C" void kernel_launch(void* const* d_in, const int* in_sizes, int n_in,
                              void* d_out, int out_size, void* d_ws, size_t ws_size,
                              hipStream_t stream) {
  const float* x    = (const float*)d_in[0];
  const float* Ws   = (const float*)d_in[1];
  const float* bs   = (const float*)d_in[2];
  const float* Wg   = (const float*)d_in[3];
  const float* bg   = (const float*)d_in[4];
  const float* Wn1  = (const float*)d_in[5];
  const float* bn1  = (const float*)d_in[6];
  const float* Wn2  = (const float*)d_in[7];
  const float* bn2  = (const float*)d_in[8];
  const int* dsid   = (const int*)d_in[10];

  float* out    = (float*)d_out;
  float* g_head = out;
  float* g_var  = out + (size_t)N_GRAPHS * 50;
  float* n_head = out + (size_t)2 * N_GRAPHS * 50;
  float* n_var  = n_head + (size_t)N_NODES * 3;

  char* ws = (char*)d_ws;
  int* perm = (int*)(ws);                                   // 16384
  int* meta = (int*)(ws + 16384);                           // 256
  unsigned short* W1Tf = (unsigned short*)(ws + 16640);     // 2,097,152
  unsigned short* WsTf = (unsigned short*)(ws + 2113792);   // 2,097,152
  unsigned short* WgT  = (unsigned short*)(ws + 4210944);   // 524,288
  unsigned short* xg   = (unsigned short*)(ws + 4735232);   // 4,194,304
  unsigned short* hg   = (unsigned short*)(ws + 8929536);   // 4,194,304
  if (ws_size < 13123840) return;

  bucket_kernel<<<dim3(1), dim3(256), 0, stream>>>(dsid, perm, meta);
  prep_wf_kernel<<<dim3(256), dim3(256), 0, stream>>>(Wn1, Ws, W1Tf, WsTf);
  prep_wg_kernel<<<dim3(1024), dim3(256), 0, stream>>>(Wg, WgT);
  node_kernel<<<dim3(NT_MAX), dim3(512), 0, stream>>>(
      x, meta, perm, W1Tf, bn1, Wn2, bn2, xg, n_head, n_var);
  gstage1_kernel<<<dim3(GT_MAX), dim3(512), 0, stream>>>(
      xg, meta, perm, WsTf, bs, hg);
  gstage2_kernel<<<dim3(G2_MAX), dim3(256), 0, stream>>>(
      meta, perm, hg, WgT, bg, g_head, g_var);
}